// Round 3
// baseline (166.181 us; speedup 1.0000x reference)
//
#include <hip/hip_runtime.h>
#include <hip/hip_fp16.h>

#define NTOT 8192
#define NHALF 4096
#define DIM 256
#define LOG2E 1.4426950408889634f
#define LN2f 0.6931471805599453f
#define NEG_BIG -1e30f
#define COLSPLIT 8
#define BM 128
#define BN 64
#define CPB (NTOT / COLSPLIT)            /* 1024 cols per block */
#define NTILES (CPB / BN)                /* 16 tiles per block  */
#define NBLK ((NTOT / BM) * COLSPLIT)    /* 64 x 8 = 512 blocks */

typedef _Float16 half8 __attribute__((ext_vector_type(8)));
typedef float floatx4 __attribute__((ext_vector_type(4)));

// ---------------- normalize: z1|z2 -> fp16 unit rows; re-arm counter ----------------
__global__ __launch_bounds__(256) void k_normalize(const float* __restrict__ z1,
                                                   const float* __restrict__ z2,
                                                   __half* __restrict__ zn,
                                                   unsigned int* __restrict__ cnt) {
  if (blockIdx.x == 0 && threadIdx.x == 0) *cnt = 0;
  int row = blockIdx.x * 4 + (threadIdx.x >> 6);
  int lane = threadIdx.x & 63;
  const float* src = (row < NHALF) ? (z1 + (size_t)row * DIM)
                                   : (z2 + (size_t)(row - NHALF) * DIM);
  float4 v = ((const float4*)src)[lane];
  float ss = v.x * v.x + v.y * v.y + v.z * v.z + v.w * v.w;
#pragma unroll
  for (int m = 1; m < 64; m <<= 1) ss += __shfl_xor(ss, m);
  float inv = 1.0f / fmaxf(sqrtf(ss), 1e-8f);
  __half2 h0, h1;
  h0.x = __float2half_rn(v.x * inv);
  h0.y = __float2half_rn(v.y * inv);
  h1.x = __float2half_rn(v.z * inv);
  h1.y = __float2half_rn(v.w * inv);
  __half2* dst = (__half2*)(zn + (size_t)row * DIM + lane * 4);
  dst[0] = h0;
  dst[1] = h1;
}

// Fixed-base softmax update: L += 2^(v*kk); Mx = running max of raw v.
// MODE 0: hot path. MODE 1: tile contains this wave's diag cols (mask).
// MODE 2: tile contains this wave's target cols (capture t bit-exactly).
template <int MODE>
__device__ __forceinline__ void upd(const floatx4 (&acc)[2][4], float (&Mx)[8],
                                    float (&L)[8], float* __restrict__ tS,
                                    int R0, int colT, int cl, int quad, int off,
                                    float kk) {
#pragma unroll
  for (int rt = 0; rt < 2; rt++) {
#pragma unroll
    for (int r = 0; r < 4; r++) {
      const int s = rt * 4 + r;
      const int grow = R0 + rt * 16 + quad * 4 + r;
      float v0 = acc[rt][0][r], v1 = acc[rt][1][r];
      float v2 = acc[rt][2][r], v3 = acc[rt][3][r];
      const int c0 = colT + cl;
      if (MODE == 2) {
        const int tc = grow + off;
        if (c0 == tc) tS[grow] = v0;
        if (c0 + 16 == tc) tS[grow] = v1;
        if (c0 + 32 == tc) tS[grow] = v2;
        if (c0 + 48 == tc) tS[grow] = v3;
      }
      if (MODE == 1) {
        v0 = (c0 == grow) ? NEG_BIG : v0;
        v1 = (c0 + 16 == grow) ? NEG_BIG : v1;
        v2 = (c0 + 32 == grow) ? NEG_BIG : v2;
        v3 = (c0 + 48 == grow) ? NEG_BIG : v3;  // exp2(big*kk) flushes to 0
      }
      Mx[s] = fmaxf(fmaxf(Mx[s], fmaxf(v0, v1)), fmaxf(v2, v3));  // 2x v_max3
      L[s] += (exp2f(v0 * kk) + exp2f(v1 * kk)) + (exp2f(v2 * kk) + exp2f(v3 * kk));
    }
  }
}

// ---------------- main fused S-pass + last-block final reduce ----------------
// grid = 64 rowTiles x 8 colSplits = 512 blocks, 256 threads (4 waves x 32 rows)
__global__ __launch_bounds__(256, 2) void k_main(
    const __half* __restrict__ zn, const float* __restrict__ logT,
    float* __restrict__ tS, float* __restrict__ pM, float* __restrict__ pL,
    unsigned int* __restrict__ cnt, float* __restrict__ out) {
  __shared__ uint4 lds[BN * 32];  // 64 rows x 32 x 16B = 32 KB, xor-swizzled
  __shared__ int lastFlag;

  const int bid = blockIdx.x;
  const int rowTile = bid >> 3;
  const int colq = bid & 7;
  const int rowBase = rowTile * BM;
  const int colBase = colq * CPB;
  const int tid = threadIdx.x;
  const int w = tid >> 6;
  const int lane = tid & 63;
  const int quad = lane >> 4;
  const int cl = lane & 15;

  const float invT = expf(-logT[0]);
  const float kk = invT * LOG2E;

  const int R0 = rowBase + w * 32;
  const int off = (R0 < NHALF) ? NHALF : -NHALF;

  // A fragments in registers: wave owns rows [R0, R0+32), 2 tiles of 16
  half8 a[2][8];
#pragma unroll
  for (int ks = 0; ks < 8; ks++) {
    a[0][ks] = *(const half8*)(zn + (size_t)(R0 + cl) * DIM + ks * 32 + quad * 8);
    a[1][ks] = *(const half8*)(zn + (size_t)(R0 + 16 + cl) * DIM + ks * 32 + quad * 8);
  }

  float Mx[8], L[8];
#pragma unroll
  for (int s = 0; s < 8; s++) { Mx[s] = NEG_BIG; L[s] = 0.f; }

  for (int t = 0; t < NTILES; t++) {
    __syncthreads();
    // stage B tile: 64 rows x 512B, reg-staged; xor-swizzle chunk idx on write
#pragma unroll
    for (int i = 0; i < 8; i++) {
      int idx = tid + i * 256;
      int c = idx >> 5, ch = idx & 31;
      int g = colBase + t * BN + c;
      uint4 v = *(const uint4*)(zn + (size_t)g * DIM + ch * 8);
      lds[c * 32 + (ch ^ (c & 7))] = v;
    }
    __syncthreads();

    floatx4 acc[2][4];
#pragma unroll
    for (int rt = 0; rt < 2; rt++)
#pragma unroll
      for (int nt = 0; nt < 4; nt++) acc[rt][nt] = (floatx4){0.f, 0.f, 0.f, 0.f};

#pragma unroll
    for (int nt = 0; nt < 4; nt++) {
      const int bc = nt * 16 + cl;
#pragma unroll
      for (int ks = 0; ks < 8; ks++) {
        const int ch = ks * 4 + quad;
        half8 b = *(const half8*)&lds[bc * 32 + (ch ^ (bc & 7))];
        acc[0][nt] = __builtin_amdgcn_mfma_f32_16x16x32_f16(a[0][ks], b, acc[0][nt], 0, 0, 0);
        acc[1][nt] = __builtin_amdgcn_mfma_f32_16x16x32_f16(a[1][ks], b, acc[1][nt], 0, 0, 0);
      }
    }

    const int colT = colBase + t * BN;
    const bool diagHit = (R0 < colT + BN) && (colT < R0 + 32);
    const int T0 = R0 + off;
    const bool tgtHit = (T0 < colT + BN) && (colT < T0 + 32);
    if (diagHit)      upd<1>(acc, Mx, L, tS, R0, colT, cl, quad, off, kk);
    else if (tgtHit)  upd<2>(acc, Mx, L, tS, R0, colT, cl, quad, off, kk);
    else              upd<0>(acc, Mx, L, tS, R0, colT, cl, quad, off, kk);
  }

  // combine 16 per-lane partials within each quad (pure max + add)
#pragma unroll
  for (int s = 0; s < 8; s++) {
    float m = Mx[s], l = L[s];
#pragma unroll
    for (int sh = 1; sh < 16; sh <<= 1) {
      m = fmaxf(m, __shfl_xor(m, sh));
      l += __shfl_xor(l, sh);
    }
    Mx[s] = m;
    L[s] = l;
  }
  if (cl == 0) {
#pragma unroll
    for (int rt = 0; rt < 2; rt++)
#pragma unroll
      for (int r = 0; r < 4; r++) {
        const int grow = R0 + rt * 16 + quad * 4 + r;
        const int s = rt * 4 + r;
        pM[colq * NTOT + grow] = Mx[s];
        pL[colq * NTOT + grow] = L[s];
      }
  }

  // ---- deadlock-free "last block reduces": never waits on co-residency ----
  __threadfence();
  __syncthreads();
  if (tid == 0) {
    unsigned prev = __hip_atomic_fetch_add(cnt, 1u, __ATOMIC_ACQ_REL,
                                           __HIP_MEMORY_SCOPE_AGENT);
    lastFlag = (prev == (unsigned)(NBLK - 1)) ? 1 : 0;
  }
  __syncthreads();
  if (!lastFlag) return;

  float lossSum = 0.f, corrSum = 0.f;
  for (int rr = 0; rr < NTOT / 256; rr++) {
    const int row = rr * 256 + tid;
    float m = NEG_BIG, Lr = 0.f;
#pragma unroll
    for (int q = 0; q < COLSPLIT; q++) {
      m = fmaxf(m, pM[q * NTOT + row]);
      Lr += pL[q * NTOT + row];
    }
    const float tp = tS[row];
    lossSum += LN2f * log2f(Lr) - tp * invT;   // -log p_target
    corrSum += (tp >= m) ? 1.f : 0.f;          // bit-exact: same MFMA values
  }
  float* sl = (float*)lds;  // reuse LDS for the block reduction
  float* sc = sl + 256;
  sl[tid] = lossSum;
  sc[tid] = corrSum;
  __syncthreads();
  for (int s2 = 128; s2 > 0; s2 >>= 1) {
    if (tid < s2) { sl[tid] += sl[tid + s2]; sc[tid] += sc[tid + s2]; }
    __syncthreads();
  }
  if (tid == 0) {
    out[0] = sl[0] * (1.0f / (float)NTOT);
    out[1] = sc[0] * 0.5f;
  }
}

extern "C" void kernel_launch(void* const* d_in, const int* in_sizes, int n_in,
                              void* d_out, int out_size, void* d_ws, size_t ws_size,
                              hipStream_t stream) {
  const float* z1 = (const float*)d_in[0];
  const float* z2 = (const float*)d_in[1];
  const float* logT = (const float*)d_in[2];

  // workspace layout (~4.56 MB)
  char* ws = (char*)d_ws;
  __half* zn = (__half*)ws;                                   // 4 MB unit rows
  float* tS = (float*)(ws + (size_t)(4 << 20));               // 32 KB target sims
  float* pM = (float*)(ws + (size_t)(4 << 20) + (32 << 10));  // 256 KB
  float* pL = pM + COLSPLIT * NTOT;                           // 256 KB
  unsigned int* cnt = (unsigned int*)(pL + COLSPLIT * NTOT);  // 4 B

  k_normalize<<<NTOT / 4, 256, 0, stream>>>(z1, z2, zn, cnt);
  k_main<<<NBLK, 256, 0, stream>>>(zn, logT, tS, pM, pL, cnt, (float*)d_out);
}

// Round 4
// 155.510 us; speedup vs baseline: 1.0686x; 1.0686x over previous
//
#include <hip/hip_runtime.h>
#include <hip/hip_fp16.h>

#define NTOT 8192
#define NHALF 4096
#define DIM 256
#define LOG2E 1.4426950408889634f
#define LN2f 0.6931471805599453f
#define NEG_BIG -1e30f
#define COLSPLIT 8
#define BM 128
#define BN 64
#define CPB (NTOT / COLSPLIT)            /* 1024 cols per block */
#define NTILES (CPB / BN)                /* 16 tiles per block  */
#define NBLK ((NTOT / BM) * COLSPLIT)    /* 64 x 8 = 512 blocks */

typedef _Float16 half8 __attribute__((ext_vector_type(8)));
typedef float floatx4 __attribute__((ext_vector_type(4)));

// ---------------- normalize: z1|z2 -> fp16 unit rows; re-arm counter ----------------
__global__ __launch_bounds__(256) void k_normalize(const float* __restrict__ z1,
                                                   const float* __restrict__ z2,
                                                   __half* __restrict__ zn,
                                                   unsigned int* __restrict__ cnt) {
  if (blockIdx.x == 0 && threadIdx.x == 0) *cnt = 0;
  int row = blockIdx.x * 4 + (threadIdx.x >> 6);
  int lane = threadIdx.x & 63;
  const float* src = (row < NHALF) ? (z1 + (size_t)row * DIM)
                                   : (z2 + (size_t)(row - NHALF) * DIM);
  float4 v = ((const float4*)src)[lane];
  float ss = v.x * v.x + v.y * v.y + v.z * v.z + v.w * v.w;
#pragma unroll
  for (int m = 1; m < 64; m <<= 1) ss += __shfl_xor(ss, m);
  float inv = 1.0f / fmaxf(sqrtf(ss), 1e-8f);
  __half2 h0, h1;
  h0.x = __float2half_rn(v.x * inv);
  h0.y = __float2half_rn(v.y * inv);
  h1.x = __float2half_rn(v.z * inv);
  h1.y = __float2half_rn(v.w * inv);
  __half2* dst = (__half2*)(zn + (size_t)row * DIM + lane * 4);
  dst[0] = h0;
  dst[1] = h1;
}

// ---------------- main fused S-pass + last-block final reduce ----------------
// grid = 64 rowTiles x 8 colSplits = 512 blocks, 256 threads (4 waves x 32 rows)
__global__ __launch_bounds__(256, 2) void k_main(
    const __half* __restrict__ zn, const float* __restrict__ logT,
    float* __restrict__ tS, float* __restrict__ pM, float* __restrict__ pL,
    unsigned int* __restrict__ cnt, float* __restrict__ out) {
  __shared__ uint4 lds[BN * 32];  // 64 rows x 32 x 16B = 32 KB, xor-swizzled
  __shared__ int lastFlag;

  const int bid = blockIdx.x;
  const int rowTile = bid >> 3;
  const int colq = bid & 7;
  const int rowBase = rowTile * BM;
  const int colBase = colq * CPB;
  const int tid = threadIdx.x;
  const int w = tid >> 6;
  const int lane = tid & 63;
  const int quad = lane >> 4;
  const int cl = lane & 15;

  const float invT = expf(-logT[0]);
  const float kk = invT * LOG2E;

  const int R0 = rowBase + w * 32;
  const int off = (R0 < NHALF) ? NHALF : -NHALF;
  const int T0 = R0 + off;  // this wave's 32 target cols: [T0, T0+32)

  // A fragments in registers: wave owns rows [R0, R0+32), 2 tiles of 16
  half8 a[2][8];
#pragma unroll
  for (int ks = 0; ks < 8; ks++) {
    a[0][ks] = *(const half8*)(zn + (size_t)(R0 + cl) * DIM + ks * 32 + quad * 8);
    a[1][ks] = *(const half8*)(zn + (size_t)(R0 + 16 + cl) * DIM + ks * 32 + quad * 8);
  }

  float Mx[8], L[8];
#pragma unroll
  for (int s = 0; s < 8; s++) { Mx[s] = NEG_BIG; L[s] = 0.f; }

  for (int t = 0; t < NTILES; t++) {
    __syncthreads();
    // stage B tile: 64 rows x 512B, reg-staged; xor-swizzle chunk idx on write
#pragma unroll
    for (int i = 0; i < 8; i++) {
      int idx = tid + i * 256;
      int c = idx >> 5, ch = idx & 31;
      int g = colBase + t * BN + c;
      uint4 v = *(const uint4*)(zn + (size_t)g * DIM + ch * 8);
      lds[c * 32 + (ch ^ (c & 7))] = v;
    }
    __syncthreads();

    floatx4 acc[2][4];
#pragma unroll
    for (int rt = 0; rt < 2; rt++)
#pragma unroll
      for (int nt = 0; nt < 4; nt++) acc[rt][nt] = (floatx4){0.f, 0.f, 0.f, 0.f};

#pragma unroll
    for (int nt = 0; nt < 4; nt++) {
      const int bc = nt * 16 + cl;
#pragma unroll
      for (int ks = 0; ks < 8; ks++) {
        const int ch = ks * 4 + quad;
        half8 b = *(const half8*)&lds[bc * 32 + (ch ^ (bc & 7))];
        acc[0][nt] = __builtin_amdgcn_mfma_f32_16x16x32_f16(a[0][ks], b, acc[0][nt], 0, 0, 0);
        acc[1][nt] = __builtin_amdgcn_mfma_f32_16x16x32_f16(a[1][ks], b, acc[1][nt], 0, 0, 0);
      }
    }

    // ---- straight-line update (single basic block, like the 70.6us kernel):
    // unconditional diag mask + fixed-base softmax (L += 2^(v*kk), no rescale)
    const int colT = colBase + t * BN;
    const int c0 = colT + cl;
#pragma unroll
    for (int rt = 0; rt < 2; rt++) {
#pragma unroll
      for (int r = 0; r < 4; r++) {
        const int s = rt * 4 + r;
        const int grow = R0 + rt * 16 + quad * 4 + r;
        float v0 = acc[rt][0][r], v1 = acc[rt][1][r];
        float v2 = acc[rt][2][r], v3 = acc[rt][3][r];
        v0 = (c0 == grow) ? NEG_BIG : v0;
        v1 = (c0 + 16 == grow) ? NEG_BIG : v1;
        v2 = (c0 + 32 == grow) ? NEG_BIG : v2;
        v3 = (c0 + 48 == grow) ? NEG_BIG : v3;  // exp2(v*kk) flushes to 0
        Mx[s] = fmaxf(fmaxf(Mx[s], fmaxf(v0, v1)), fmaxf(v2, v3));  // 2x v_max3
        L[s] += (exp2f(v0 * kk) + exp2f(v1 * kk)) + (exp2f(v2 * kk) + exp2f(v3 * kk));
      }
    }
    // rare wave-uniform capture of the exact MFMA target similarity (1/16 tiles
    // in 1/8 blocks); appended AFTER the hot update so the hot path stays linear
    if ((unsigned)(T0 - colT) < (unsigned)BN) {
#pragma unroll
      for (int rt = 0; rt < 2; rt++)
#pragma unroll
        for (int r = 0; r < 4; r++) {
          const int grow = R0 + rt * 16 + quad * 4 + r;
          const int tc = grow + off;
          if (c0 == tc) tS[grow] = acc[rt][0][r];
          if (c0 + 16 == tc) tS[grow] = acc[rt][1][r];
          if (c0 + 32 == tc) tS[grow] = acc[rt][2][r];
          if (c0 + 48 == tc) tS[grow] = acc[rt][3][r];
        }
    }
  }

  // combine 16 per-lane partials within each quad (pure max + add)
#pragma unroll
  for (int s = 0; s < 8; s++) {
    float m = Mx[s], l = L[s];
#pragma unroll
    for (int sh = 1; sh < 16; sh <<= 1) {
      m = fmaxf(m, __shfl_xor(m, sh));
      l += __shfl_xor(l, sh);
    }
    Mx[s] = m;
    L[s] = l;
  }
  if (cl == 0) {
#pragma unroll
    for (int rt = 0; rt < 2; rt++)
#pragma unroll
      for (int r = 0; r < 4; r++) {
        const int grow = R0 + rt * 16 + quad * 4 + r;
        const int s = rt * 4 + r;
        pM[colq * NTOT + grow] = Mx[s];   // coalesced partial layout
        pL[colq * NTOT + grow] = L[s];
      }
  }

  // ---- deadlock-free "last block reduces": never waits on co-residency ----
  __threadfence();
  __syncthreads();
  if (tid == 0) {
    unsigned prev = __hip_atomic_fetch_add(cnt, 1u, __ATOMIC_ACQ_REL,
                                           __HIP_MEMORY_SCOPE_AGENT);
    lastFlag = (prev == (unsigned)(NBLK - 1)) ? 1 : 0;
  }
  __syncthreads();
  if (!lastFlag) return;

  // final reduce over col-splits, vectorized float4 (8192 rows / 256 thr / 4)
  const float4* pM4 = (const float4*)pM;
  const float4* pL4 = (const float4*)pL;
  const float4* tS4 = (const float4*)tS;
  float lossSum = 0.f, corrSum = 0.f;
  for (int it = 0; it < NTOT / (256 * 4); it++) {
    const int r4 = it * 256 + tid;  // float4 index; rows 4*r4..4*r4+3
    float4 m = make_float4(NEG_BIG, NEG_BIG, NEG_BIG, NEG_BIG);
    float4 Ls = make_float4(0.f, 0.f, 0.f, 0.f);
#pragma unroll
    for (int q = 0; q < COLSPLIT; q++) {
      float4 mq = pM4[q * (NTOT / 4) + r4];
      float4 lq = pL4[q * (NTOT / 4) + r4];
      m.x = fmaxf(m.x, mq.x); m.y = fmaxf(m.y, mq.y);
      m.z = fmaxf(m.z, mq.z); m.w = fmaxf(m.w, mq.w);
      Ls.x += lq.x; Ls.y += lq.y; Ls.z += lq.z; Ls.w += lq.w;
    }
    float4 tp = tS4[r4];
    lossSum += (LN2f * log2f(Ls.x) - tp.x * invT) +
               (LN2f * log2f(Ls.y) - tp.y * invT) +
               (LN2f * log2f(Ls.z) - tp.z * invT) +
               (LN2f * log2f(Ls.w) - tp.w * invT);
    corrSum += ((tp.x >= m.x) ? 1.f : 0.f) + ((tp.y >= m.y) ? 1.f : 0.f) +
               ((tp.z >= m.z) ? 1.f : 0.f) + ((tp.w >= m.w) ? 1.f : 0.f);
  }
  float* sl = (float*)lds;  // reuse LDS for the block reduction
  float* sc = sl + 256;
  sl[tid] = lossSum;
  sc[tid] = corrSum;
  __syncthreads();
  for (int s2 = 128; s2 > 0; s2 >>= 1) {
    if (tid < s2) { sl[tid] += sl[tid + s2]; sc[tid] += sc[tid + s2]; }
    __syncthreads();
  }
  if (tid == 0) {
    out[0] = sl[0] * (1.0f / (float)NTOT);
    out[1] = sc[0] * 0.5f;
  }
}

extern "C" void kernel_launch(void* const* d_in, const int* in_sizes, int n_in,
                              void* d_out, int out_size, void* d_ws, size_t ws_size,
                              hipStream_t stream) {
  const float* z1 = (const float*)d_in[0];
  const float* z2 = (const float*)d_in[1];
  const float* logT = (const float*)d_in[2];

  // workspace layout (~4.56 MB)
  char* ws = (char*)d_ws;
  __half* zn = (__half*)ws;                                   // 4 MB unit rows
  float* tS = (float*)(ws + (size_t)(4 << 20));               // 32 KB target sims
  float* pM = (float*)(ws + (size_t)(4 << 20) + (32 << 10));  // 256 KB
  float* pL = pM + COLSPLIT * NTOT;                           // 256 KB
  unsigned int* cnt = (unsigned int*)(pL + COLSPLIT * NTOT);  // 4 B

  k_normalize<<<NTOT / 4, 256, 0, stream>>>(z1, z2, zn, cnt);
  k_main<<<NBLK, 256, 0, stream>>>(zn, logT, tS, pM, pL, cnt, (float*)d_out);
}

// Round 5
// 152.588 us; speedup vs baseline: 1.0891x; 1.0191x over previous
//
#include <hip/hip_runtime.h>
#include <hip/hip_fp16.h>

#define NTOT 8192
#define NHALF 4096
#define DIM 256
#define LOG2E 1.4426950408889634f
#define LN2f 0.6931471805599453f
#define NEG_BIG -1e30f
#define COLSPLIT 8
#define BM 128
#define BN 64
#define CPB (NTOT / COLSPLIT)            /* 1024 cols per block */
#define NTILES (CPB / BN)                /* 16 tiles per block  */
#define NBLK ((NTOT / BM) * COLSPLIT)    /* 64 x 8 = 512 blocks */

typedef _Float16 half8 __attribute__((ext_vector_type(8)));
typedef float floatx4 __attribute__((ext_vector_type(4)));

// ---------------- normalize: z1|z2 -> fp16 unit rows; re-arm counter ----------------
__global__ __launch_bounds__(256) void k_normalize(const float* __restrict__ z1,
                                                   const float* __restrict__ z2,
                                                   __half* __restrict__ zn,
                                                   unsigned int* __restrict__ cnt) {
  if (blockIdx.x == 0 && threadIdx.x == 0) *cnt = 0;
  int row = blockIdx.x * 4 + (threadIdx.x >> 6);
  int lane = threadIdx.x & 63;
  const float* src = (row < NHALF) ? (z1 + (size_t)row * DIM)
                                   : (z2 + (size_t)(row - NHALF) * DIM);
  float4 v = ((const float4*)src)[lane];
  float ss = v.x * v.x + v.y * v.y + v.z * v.z + v.w * v.w;
#pragma unroll
  for (int m = 1; m < 64; m <<= 1) ss += __shfl_xor(ss, m);
  float inv = 1.0f / fmaxf(sqrtf(ss), 1e-8f);
  __half2 h0, h1;
  h0.x = __float2half_rn(v.x * inv);
  h0.y = __float2half_rn(v.y * inv);
  h1.x = __float2half_rn(v.z * inv);
  h1.y = __float2half_rn(v.w * inv);
  __half2* dst = (__half2*)(zn + (size_t)row * DIM + lane * 4);
  dst[0] = h0;
  dst[1] = h1;
}

// ---------------- main fused S-pass + last-block final reduce ----------------
// grid = 64 rowTiles x 8 colSplits = 512 blocks, 256 threads (4 waves x 32 rows)
// Double-buffered LDS: global loads for tile t+1 issued into st[8] registers
// BEFORE the MFMA/update on tile t, so L2 latency hides under compute.
__global__ __launch_bounds__(256, 2) void k_main(
    const __half* __restrict__ zn, const float* __restrict__ logT,
    float* __restrict__ tS, float* __restrict__ pM, float* __restrict__ pL,
    unsigned int* __restrict__ cnt, float* __restrict__ out) {
  __shared__ uint4 lds[2][BN * 32];  // 2 x 32 KB double buffer, xor-swizzled
  __shared__ int lastFlag;

  const int bid = blockIdx.x;
  const int rowTile = bid >> 3;
  const int colq = bid & 7;
  const int rowBase = rowTile * BM;
  const int colBase = colq * CPB;
  const int tid = threadIdx.x;
  const int w = tid >> 6;
  const int lane = tid & 63;
  const int quad = lane >> 4;
  const int cl = lane & 15;

  const float invT = expf(-logT[0]);
  const float kk = invT * LOG2E;

  const int R0 = rowBase + w * 32;
  const int off = (R0 < NHALF) ? NHALF : -NHALF;
  const int T0 = R0 + off;  // this wave's 32 target cols: [T0, T0+32)

  // A fragments in registers: wave owns rows [R0, R0+32), 2 tiles of 16
  half8 a[2][8];
#pragma unroll
  for (int ks = 0; ks < 8; ks++) {
    a[0][ks] = *(const half8*)(zn + (size_t)(R0 + cl) * DIM + ks * 32 + quad * 8);
    a[1][ks] = *(const half8*)(zn + (size_t)(R0 + 16 + cl) * DIM + ks * 32 + quad * 8);
  }

  // staging geometry: chunk i covers row c = (tid>>5) + 8*i, 16B piece ch = tid&31.
  // Both ch and the swizzle term (c&7) == (tid>>5)&7 are invariant across i.
  const int ch = tid & 31;
  const int c0r = tid >> 5;
  const int ldsBase = c0r * 32 + (ch ^ (c0r & 7));  // + i*256 per chunk
  const __half* gB = zn + (size_t)(colBase + c0r) * DIM + ch * 8;
  // tile t, chunk i: gB + t*BN*DIM + i*8*DIM

  float Mx[8], L[8];
#pragma unroll
  for (int s = 0; s < 8; s++) { Mx[s] = NEG_BIG; L[s] = 0.f; }

  uint4 st[8];
  // ---- prologue: stage tile 0 into lds[0] ----
#pragma unroll
  for (int i = 0; i < 8; i++)
    st[i] = *(const uint4*)(gB + (size_t)i * 8 * DIM);
#pragma unroll
  for (int i = 0; i < 8; i++)
    lds[0][ldsBase + i * 256] = st[i];
  __syncthreads();

  for (int t = 0; t < NTILES; t++) {
    const int cur = t & 1;

    // issue next tile's loads early (8 independent dwordx4, kept in flight)
    if (t + 1 < NTILES) {
#pragma unroll
      for (int i = 0; i < 8; i++)
        st[i] = *(const uint4*)(gB + ((size_t)(t + 1) * BN + (size_t)i * 8) * DIM);
    }

    floatx4 acc[2][4];
#pragma unroll
    for (int rt = 0; rt < 2; rt++)
#pragma unroll
      for (int nt = 0; nt < 4; nt++) acc[rt][nt] = (floatx4){0.f, 0.f, 0.f, 0.f};

#pragma unroll
    for (int nt = 0; nt < 4; nt++) {
      const int bc = nt * 16 + cl;
#pragma unroll
      for (int ks = 0; ks < 8; ks++) {
        const int kc = ks * 4 + quad;
        half8 b = *(const half8*)&lds[cur][bc * 32 + (kc ^ (bc & 7))];
        acc[0][nt] = __builtin_amdgcn_mfma_f32_16x16x32_f16(a[0][ks], b, acc[0][nt], 0, 0, 0);
        acc[1][nt] = __builtin_amdgcn_mfma_f32_16x16x32_f16(a[1][ks], b, acc[1][nt], 0, 0, 0);
      }
    }

    // ---- straight-line update: unconditional diag mask + fixed-base softmax ----
    const int colT = colBase + t * BN;
    const int c0 = colT + cl;
#pragma unroll
    for (int rt = 0; rt < 2; rt++) {
#pragma unroll
      for (int r = 0; r < 4; r++) {
        const int s = rt * 4 + r;
        const int grow = R0 + rt * 16 + quad * 4 + r;
        float v0 = acc[rt][0][r], v1 = acc[rt][1][r];
        float v2 = acc[rt][2][r], v3 = acc[rt][3][r];
        v0 = (c0 == grow) ? NEG_BIG : v0;
        v1 = (c0 + 16 == grow) ? NEG_BIG : v1;
        v2 = (c0 + 32 == grow) ? NEG_BIG : v2;
        v3 = (c0 + 48 == grow) ? NEG_BIG : v3;  // exp2(v*kk) flushes to 0
        Mx[s] = fmaxf(fmaxf(Mx[s], fmaxf(v0, v1)), fmaxf(v2, v3));  // 2x v_max3
        L[s] += (exp2f(v0 * kk) + exp2f(v1 * kk)) + (exp2f(v2 * kk) + exp2f(v3 * kk));
      }
    }
    // rare wave-uniform capture of the exact MFMA target similarity
    if ((unsigned)(T0 - colT) < (unsigned)BN) {
#pragma unroll
      for (int rt = 0; rt < 2; rt++)
#pragma unroll
        for (int r = 0; r < 4; r++) {
          const int grow = R0 + rt * 16 + quad * 4 + r;
          const int tc = grow + off;
          if (c0 == tc) tS[grow] = acc[rt][0][r];
          if (c0 + 16 == tc) tS[grow] = acc[rt][1][r];
          if (c0 + 32 == tc) tS[grow] = acc[rt][2][r];
          if (c0 + 48 == tc) tS[grow] = acc[rt][3][r];
        }
    }

    // write next tile into the other buffer; one barrier per tile
    if (t + 1 < NTILES) {
#pragma unroll
      for (int i = 0; i < 8; i++)
        lds[cur ^ 1][ldsBase + i * 256] = st[i];
      __syncthreads();
    }
  }

  // combine 16 per-lane partials within each quad (pure max + add)
#pragma unroll
  for (int s = 0; s < 8; s++) {
    float m = Mx[s], l = L[s];
#pragma unroll
    for (int sh = 1; sh < 16; sh <<= 1) {
      m = fmaxf(m, __shfl_xor(m, sh));
      l += __shfl_xor(l, sh);
    }
    Mx[s] = m;
    L[s] = l;
  }
  if (cl == 0) {
#pragma unroll
    for (int rt = 0; rt < 2; rt++)
#pragma unroll
      for (int r = 0; r < 4; r++) {
        const int grow = R0 + rt * 16 + quad * 4 + r;
        const int s = rt * 4 + r;
        pM[colq * NTOT + grow] = Mx[s];   // coalesced partial layout
        pL[colq * NTOT + grow] = L[s];
      }
  }

  // ---- deadlock-free "last block reduces": never waits on co-residency ----
  __threadfence();
  __syncthreads();
  if (tid == 0) {
    unsigned prev = __hip_atomic_fetch_add(cnt, 1u, __ATOMIC_ACQ_REL,
                                           __HIP_MEMORY_SCOPE_AGENT);
    lastFlag = (prev == (unsigned)(NBLK - 1)) ? 1 : 0;
  }
  __syncthreads();
  if (!lastFlag) return;

  // final reduce over col-splits, vectorized float4 (8192 rows / 256 thr / 4)
  const float4* pM4 = (const float4*)pM;
  const float4* pL4 = (const float4*)pL;
  const float4* tS4 = (const float4*)tS;
  float lossSum = 0.f, corrSum = 0.f;
  for (int it = 0; it < NTOT / (256 * 4); it++) {
    const int r4 = it * 256 + tid;  // float4 index; rows 4*r4..4*r4+3
    float4 m = make_float4(NEG_BIG, NEG_BIG, NEG_BIG, NEG_BIG);
    float4 Ls = make_float4(0.f, 0.f, 0.f, 0.f);
#pragma unroll
    for (int q = 0; q < COLSPLIT; q++) {
      float4 mq = pM4[q * (NTOT / 4) + r4];
      float4 lq = pL4[q * (NTOT / 4) + r4];
      m.x = fmaxf(m.x, mq.x); m.y = fmaxf(m.y, mq.y);
      m.z = fmaxf(m.z, mq.z); m.w = fmaxf(m.w, mq.w);
      Ls.x += lq.x; Ls.y += lq.y; Ls.z += lq.z; Ls.w += lq.w;
    }
    float4 tp = tS4[r4];
    lossSum += (LN2f * log2f(Ls.x) - tp.x * invT) +
               (LN2f * log2f(Ls.y) - tp.y * invT) +
               (LN2f * log2f(Ls.z) - tp.z * invT) +
               (LN2f * log2f(Ls.w) - tp.w * invT);
    corrSum += ((tp.x >= m.x) ? 1.f : 0.f) + ((tp.y >= m.y) ? 1.f : 0.f) +
               ((tp.z >= m.z) ? 1.f : 0.f) + ((tp.w >= m.w) ? 1.f : 0.f);
  }
  float* sl = (float*)lds;  // reuse LDS for the block reduction
  float* sc = sl + 256;
  sl[tid] = lossSum;
  sc[tid] = corrSum;
  __syncthreads();
  for (int s2 = 128; s2 > 0; s2 >>= 1) {
    if (tid < s2) { sl[tid] += sl[tid + s2]; sc[tid] += sc[tid + s2]; }
    __syncthreads();
  }
  if (tid == 0) {
    out[0] = sl[0] * (1.0f / (float)NTOT);
    out[1] = sc[0] * 0.5f;
  }
}

extern "C" void kernel_launch(void* const* d_in, const int* in_sizes, int n_in,
                              void* d_out, int out_size, void* d_ws, size_t ws_size,
                              hipStream_t stream) {
  const float* z1 = (const float*)d_in[0];
  const float* z2 = (const float*)d_in[1];
  const float* logT = (const float*)d_in[2];

  // workspace layout (~4.56 MB)
  char* ws = (char*)d_ws;
  __half* zn = (__half*)ws;                                   // 4 MB unit rows
  float* tS = (float*)(ws + (size_t)(4 << 20));               // 32 KB target sims
  float* pM = (float*)(ws + (size_t)(4 << 20) + (32 << 10));  // 256 KB
  float* pL = pM + COLSPLIT * NTOT;                           // 256 KB
  unsigned int* cnt = (unsigned int*)(pL + COLSPLIT * NTOT);  // 4 B

  k_normalize<<<NTOT / 4, 256, 0, stream>>>(z1, z2, zn, cnt);
  k_main<<<NBLK, 256, 0, stream>>>(zn, logT, tS, pM, pL, cnt, (float*)d_out);
}

// Round 6
// 151.240 us; speedup vs baseline: 1.0988x; 1.0089x over previous
//
#include <hip/hip_runtime.h>
#include <hip/hip_fp16.h>

#define NTOT 8192
#define NHALF 4096
#define DIM 256
#define LOG2E 1.4426950408889634f
#define LN2f 0.6931471805599453f
#define NEG_BIG -1e30f
#define COLSPLIT 8
#define BM 128
#define BN 64
#define CPB (NTOT / COLSPLIT)            /* 1024 cols per block */
#define NTILES (CPB / BN)                /* 16 tiles per block  */
#define NBLK ((NTOT / BM) * COLSPLIT)    /* 64 x 8 = 512 blocks */

typedef _Float16 half8 __attribute__((ext_vector_type(8)));
typedef float floatx4 __attribute__((ext_vector_type(4)));

// ---------------- normalize: z1|z2 -> fp16 unit rows; re-arm counter ----------------
__global__ __launch_bounds__(256) void k_normalize(const float* __restrict__ z1,
                                                   const float* __restrict__ z2,
                                                   __half* __restrict__ zn,
                                                   unsigned int* __restrict__ cnt) {
  if (blockIdx.x == 0 && threadIdx.x == 0) *cnt = 0;
  int row = blockIdx.x * 4 + (threadIdx.x >> 6);
  int lane = threadIdx.x & 63;
  const float* src = (row < NHALF) ? (z1 + (size_t)row * DIM)
                                   : (z2 + (size_t)(row - NHALF) * DIM);
  float4 v = ((const float4*)src)[lane];
  float ss = v.x * v.x + v.y * v.y + v.z * v.z + v.w * v.w;
#pragma unroll
  for (int m = 1; m < 64; m <<= 1) ss += __shfl_xor(ss, m);
  float inv = 1.0f / fmaxf(sqrtf(ss), 1e-8f);
  __half2 h0, h1;
  h0.x = __float2half_rn(v.x * inv);
  h0.y = __float2half_rn(v.y * inv);
  h1.x = __float2half_rn(v.z * inv);
  h1.y = __float2half_rn(v.w * inv);
  __half2* dst = (__half2*)(zn + (size_t)row * DIM + lane * 4);
  dst[0] = h0;
  dst[1] = h1;
}

// ---------------- main fused S-pass + last-block final reduce ----------------
// grid = 64 rowTiles x 8 colSplits = 512 blocks, 256 threads (4 waves x 32 rows)
// Double-buffered LDS; prefetch loads for tile t+1 are PINNED above the MFMA
// section by sched_barrier(0) so their latency hides under tile t's compute.
__global__ __launch_bounds__(256, 2) void k_main(
    const __half* __restrict__ zn, const float* __restrict__ logT,
    float* __restrict__ tS, float* __restrict__ pM, float* __restrict__ pL,
    unsigned int* __restrict__ cnt, float* __restrict__ out) {
  __shared__ uint4 lds[2][BN * 32];  // 2 x 32 KB double buffer, xor-swizzled
  __shared__ int lastFlag;

  const int bid = blockIdx.x;
  const int rowTile = bid >> 3;
  const int colq = bid & 7;
  const int rowBase = rowTile * BM;
  const int colBase = colq * CPB;
  const int tid = threadIdx.x;
  const int w = tid >> 6;
  const int lane = tid & 63;
  const int quad = lane >> 4;
  const int cl = lane & 15;

  const float invT = expf(-logT[0]);
  const float kk = invT * LOG2E;

  const int R0 = rowBase + w * 32;
  const int off = (R0 < NHALF) ? NHALF : -NHALF;
  const int T0 = R0 + off;  // this wave's 32 target cols: [T0, T0+32)

  // A fragments in registers: wave owns rows [R0, R0+32), 2 tiles of 16
  half8 a[2][8];
#pragma unroll
  for (int ks = 0; ks < 8; ks++) {
    a[0][ks] = *(const half8*)(zn + (size_t)(R0 + cl) * DIM + ks * 32 + quad * 8);
    a[1][ks] = *(const half8*)(zn + (size_t)(R0 + 16 + cl) * DIM + ks * 32 + quad * 8);
  }

  // staging geometry: chunk i covers row c = (tid>>5) + 8*i, 16B piece ch = tid&31.
  // Both ch and the swizzle term (c&7) == (tid>>5)&7 are invariant across i.
  const int ch = tid & 31;
  const int c0r = tid >> 5;
  const int ldsBase = c0r * 32 + (ch ^ (c0r & 7));  // + i*256 per chunk
  const __half* gB = zn + (size_t)(colBase + c0r) * DIM + ch * 8;
  // tile t, chunk i: gB + (t*BN + i*8)*DIM

  float Mx[8], L[8];
#pragma unroll
  for (int s = 0; s < 8; s++) { Mx[s] = NEG_BIG; L[s] = 0.f; }

  // one tile's MFMA + straight-line softmax update (inlined at 2 call sites)
  auto compute_tile = [&](int t, const uint4* __restrict__ buf) {
    floatx4 acc[2][4];
#pragma unroll
    for (int rt = 0; rt < 2; rt++)
#pragma unroll
      for (int nt = 0; nt < 4; nt++) acc[rt][nt] = (floatx4){0.f, 0.f, 0.f, 0.f};

#pragma unroll
    for (int nt = 0; nt < 4; nt++) {
      const int bc = nt * 16 + cl;
#pragma unroll
      for (int ks = 0; ks < 8; ks++) {
        const int kc = ks * 4 + quad;
        half8 b = *(const half8*)&buf[bc * 32 + (kc ^ (bc & 7))];
        acc[0][nt] = __builtin_amdgcn_mfma_f32_16x16x32_f16(a[0][ks], b, acc[0][nt], 0, 0, 0);
        acc[1][nt] = __builtin_amdgcn_mfma_f32_16x16x32_f16(a[1][ks], b, acc[1][nt], 0, 0, 0);
      }
    }

    const int colT = colBase + t * BN;
    const int c0 = colT + cl;
#pragma unroll
    for (int rt = 0; rt < 2; rt++) {
#pragma unroll
      for (int r = 0; r < 4; r++) {
        const int s = rt * 4 + r;
        const int grow = R0 + rt * 16 + quad * 4 + r;
        float v0 = acc[rt][0][r], v1 = acc[rt][1][r];
        float v2 = acc[rt][2][r], v3 = acc[rt][3][r];
        v0 = (c0 == grow) ? NEG_BIG : v0;
        v1 = (c0 + 16 == grow) ? NEG_BIG : v1;
        v2 = (c0 + 32 == grow) ? NEG_BIG : v2;
        v3 = (c0 + 48 == grow) ? NEG_BIG : v3;  // exp2(v*kk) flushes to 0
        Mx[s] = fmaxf(fmaxf(Mx[s], fmaxf(v0, v1)), fmaxf(v2, v3));  // 2x v_max3
        L[s] += (exp2f(v0 * kk) + exp2f(v1 * kk)) + (exp2f(v2 * kk) + exp2f(v3 * kk));
      }
    }
    // rare wave-uniform capture of the exact MFMA target similarity
    if ((unsigned)(T0 - colT) < (unsigned)BN) {
#pragma unroll
      for (int rt = 0; rt < 2; rt++)
#pragma unroll
        for (int r = 0; r < 4; r++) {
          const int grow = R0 + rt * 16 + quad * 4 + r;
          const int tc = grow + off;
          if (c0 == tc) tS[grow] = acc[rt][0][r];
          if (c0 + 16 == tc) tS[grow] = acc[rt][1][r];
          if (c0 + 32 == tc) tS[grow] = acc[rt][2][r];
          if (c0 + 48 == tc) tS[grow] = acc[rt][3][r];
        }
    }
  };

  uint4 st[8];
  // ---- prologue: stage tile 0 into lds[0] ----
#pragma unroll
  for (int i = 0; i < 8; i++)
    st[i] = *(const uint4*)(gB + (size_t)i * 8 * DIM);
#pragma unroll
  for (int i = 0; i < 8; i++)
    lds[0][ldsBase + i * 256] = st[i];
  __syncthreads();

  // ---- steady state: 15 iterations, prefetch t+1 pinned above compute t ----
  for (int t = 0; t < NTILES - 1; t++) {
    const int cur = t & 1;

#pragma unroll
    for (int i = 0; i < 8; i++)
      st[i] = *(const uint4*)(gB + ((size_t)(t + 1) * BN + (size_t)i * 8) * DIM);
    // fence: loads may NOT sink below this point -> latency hides under compute
    __builtin_amdgcn_sched_barrier(0);

    compute_tile(t, lds[cur]);

#pragma unroll
    for (int i = 0; i < 8; i++)
      lds[cur ^ 1][ldsBase + i * 256] = st[i];
    __syncthreads();
  }
  // ---- epilogue: last tile, no staging ----
  compute_tile(NTILES - 1, lds[(NTILES - 1) & 1]);

  // combine 16 per-lane partials within each quad (pure max + add)
#pragma unroll
  for (int s = 0; s < 8; s++) {
    float m = Mx[s], l = L[s];
#pragma unroll
    for (int sh = 1; sh < 16; sh <<= 1) {
      m = fmaxf(m, __shfl_xor(m, sh));
      l += __shfl_xor(l, sh);
    }
    Mx[s] = m;
    L[s] = l;
  }
  if (cl == 0) {
#pragma unroll
    for (int rt = 0; rt < 2; rt++)
#pragma unroll
      for (int r = 0; r < 4; r++) {
        const int grow = R0 + rt * 16 + quad * 4 + r;
        const int s = rt * 4 + r;
        pM[colq * NTOT + grow] = Mx[s];   // coalesced partial layout
        pL[colq * NTOT + grow] = L[s];
      }
  }

  // ---- deadlock-free "last block reduces": never waits on co-residency ----
  __threadfence();
  __syncthreads();
  if (tid == 0) {
    unsigned prev = __hip_atomic_fetch_add(cnt, 1u, __ATOMIC_ACQ_REL,
                                           __HIP_MEMORY_SCOPE_AGENT);
    lastFlag = (prev == (unsigned)(NBLK - 1)) ? 1 : 0;
  }
  __syncthreads();
  if (!lastFlag) return;

  // final reduce over col-splits, vectorized float4 (8192 rows / 256 thr / 4)
  const float4* pM4 = (const float4*)pM;
  const float4* pL4 = (const float4*)pL;
  const float4* tS4 = (const float4*)tS;
  float lossSum = 0.f, corrSum = 0.f;
  for (int it = 0; it < NTOT / (256 * 4); it++) {
    const int r4 = it * 256 + tid;  // float4 index; rows 4*r4..4*r4+3
    float4 m = make_float4(NEG_BIG, NEG_BIG, NEG_BIG, NEG_BIG);
    float4 Ls = make_float4(0.f, 0.f, 0.f, 0.f);
#pragma unroll
    for (int q = 0; q < COLSPLIT; q++) {
      float4 mq = pM4[q * (NTOT / 4) + r4];
      float4 lq = pL4[q * (NTOT / 4) + r4];
      m.x = fmaxf(m.x, mq.x); m.y = fmaxf(m.y, mq.y);
      m.z = fmaxf(m.z, mq.z); m.w = fmaxf(m.w, mq.w);
      Ls.x += lq.x; Ls.y += lq.y; Ls.z += lq.z; Ls.w += lq.w;
    }
    float4 tp = tS4[r4];
    lossSum += (LN2f * log2f(Ls.x) - tp.x * invT) +
               (LN2f * log2f(Ls.y) - tp.y * invT) +
               (LN2f * log2f(Ls.z) - tp.z * invT) +
               (LN2f * log2f(Ls.w) - tp.w * invT);
    corrSum += ((tp.x >= m.x) ? 1.f : 0.f) + ((tp.y >= m.y) ? 1.f : 0.f) +
               ((tp.z >= m.z) ? 1.f : 0.f) + ((tp.w >= m.w) ? 1.f : 0.f);
  }
  float* sl = (float*)lds;  // reuse LDS for the block reduction
  float* sc = sl + 256;
  sl[tid] = lossSum;
  sc[tid] = corrSum;
  __syncthreads();
  for (int s2 = 128; s2 > 0; s2 >>= 1) {
    if (tid < s2) { sl[tid] += sl[tid + s2]; sc[tid] += sc[tid + s2]; }
    __syncthreads();
  }
  if (tid == 0) {
    out[0] = sl[0] * (1.0f / (float)NTOT);
    out[1] = sc[0] * 0.5f;
  }
}

extern "C" void kernel_launch(void* const* d_in, const int* in_sizes, int n_in,
                              void* d_out, int out_size, void* d_ws, size_t ws_size,
                              hipStream_t stream) {
  const float* z1 = (const float*)d_in[0];
  const float* z2 = (const float*)d_in[1];
  const float* logT = (const float*)d_in[2];

  // workspace layout (~4.56 MB)
  char* ws = (char*)d_ws;
  __half* zn = (__half*)ws;                                   // 4 MB unit rows
  float* tS = (float*)(ws + (size_t)(4 << 20));               // 32 KB target sims
  float* pM = (float*)(ws + (size_t)(4 << 20) + (32 << 10));  // 256 KB
  float* pL = pM + COLSPLIT * NTOT;                           // 256 KB
  unsigned int* cnt = (unsigned int*)(pL + COLSPLIT * NTOT);  // 4 B

  k_normalize<<<NTOT / 4, 256, 0, stream>>>(z1, z2, zn, cnt);
  k_main<<<NBLK, 256, 0, stream>>>(zn, logT, tS, pM, pL, cnt, (float*)d_out);
}